// Round 5
// baseline (436.137 us; speedup 1.0000x reference)
//
#include <hip/hip_runtime.h>

typedef _Float16 half_t;
typedef _Float16 h4 __attribute__((ext_vector_type(4)));

#define OUTS 7
#define NORI 8
#define NCH  256
#define FH   128
#define FW   128
#define HW   (FH * FW)
#define NSAMP (2 * OUTS * 2 * OUTS)  // 196 = 49 bins * 4 subsamples
#define NBIN  (OUTS * OUTS)          // 49
#define WBINS 13                     // bins per wave (overlapping: 0,12,24,36 starts)

struct __align__(32) Geom { int o[4]; float w[4]; };

// ---------------- transpose [N,C,H,W] f32 -> [N,H,W,C] f16 ----------------
__global__ __launch_bounds__(256) void transpose_nchw_nhwc_h(
    const float* __restrict__ in, half_t* __restrict__ out) {
  __shared__ float tile[64][65];
  const int b  = blockIdx.z;
  const int p0 = blockIdx.x * 64;
  const int c0 = blockIdx.y * 64;
  const int tx = threadIdx.x & 63;
  const int ty = threadIdx.x >> 6;

  const float* src = in + ((size_t)b * NCH + c0) * HW + p0;
#pragma unroll
  for (int i = 0; i < 16; ++i) {
    int c = ty + i * 4;
    tile[c][tx] = src[(size_t)c * HW + tx];
  }
  __syncthreads();
  half_t* dst = out + ((size_t)b * HW + p0) * NCH + c0;
#pragma unroll
  for (int i = 0; i < 16; ++i) {
    int p = ty + i * 4;
    dst[(size_t)p * NCH + tx] = (half_t)tile[tx][p];
  }
}

// ---------------- geometry precompute: one (roi, sample) per thread ------
// g[r*196 + bin*4 + sub]; byte offsets (batch folded, <<9 = *NCH*2B); weights
// pre-scaled by 0.25 (2x2 sample mean).
__global__ __launch_bounds__(256) void geom_kernel(
    const float* __restrict__ rois, Geom* __restrict__ g, int total) {
  const int gid = blockIdx.x * 256 + threadIdx.x;
  if (gid >= total) return;
  const int r   = gid / NSAMP;
  const int q   = gid - r * NSAMP;
  const int bin = q >> 2;
  const int sub = q & 3;
  const int by = bin / OUTS, bx = bin - by * OUTS;
  const int py = by * 2 + (sub >> 1);
  const int px = bx * 2 + (sub & 1);

  const float* roi = rois + (size_t)r * 6;
  const int   b     = (int)roi[0];
  const float cx    = roi[1] * 0.25f;
  const float cy    = roi[2] * 0.25f;
  const float rw    = fmaxf(roi[3] * 0.25f, 1.0f);
  const float rh    = fmaxf(roi[4] * 0.25f, 1.0f);
  const float theta = roi[5];
  const float bin_w = rw * (1.0f / OUTS);
  const float bin_h = rh * (1.0f / OUTS);
  const float ct = cosf(theta), st = sinf(theta);
  const float hbw = 0.5f * bin_w, hbh = 0.5f * bin_h;
  const float xoff = 0.25f * bin_w - 0.5f * rw;
  const float yoff = 0.25f * bin_h - 0.5f * rh;

  const float yy = (float)py * hbh + yoff;
  const float xx = (float)px * hbw + xoff;
  const float x = xx * ct + yy * st + cx;
  const float y = yy * ct - xx * st + cy;

  Geom gg;
  gg.o[0] = gg.o[1] = gg.o[2] = gg.o[3] = 0;
  gg.w[0] = gg.w[1] = gg.w[2] = gg.w[3] = 0.f;
  if (x > -1.0f && x < (float)FW && y > -1.0f && y < (float)FH) {
    float xc = fmaxf(x, 0.f);
    float yc = fmaxf(y, 0.f);
    int x0 = (int)xc;
    int y0 = (int)yc;
    int x1, y1;
    float lx, ly;
    if (x0 >= FW - 1) { x0 = FW - 1; x1 = FW - 1; lx = 0.f; }
    else              { x1 = x0 + 1; lx = xc - (float)x0; }
    if (y0 >= FH - 1) { y0 = FH - 1; y1 = FH - 1; ly = 0.f; }
    else              { y1 = y0 + 1; ly = yc - (float)y0; }
    const float wx0 = 1.f - lx, wy0 = 1.f - ly;
    gg.w[0] = 0.25f * wy0 * wx0; gg.w[1] = 0.25f * wy0 * lx;
    gg.w[2] = 0.25f * ly  * wx0; gg.w[3] = 0.25f * ly  * lx;
    const int base = b * HW;
    gg.o[0] = (base + y0 * FW + x0) << 9; gg.o[1] = (base + y0 * FW + x1) << 9;
    gg.o[2] = (base + y1 * FW + x0) << 9; gg.o[3] = (base + y1 * FW + x1) << 9;
  }
  g[gid] = gg;
}

// ---------------- main kernel ---------------------------------------------
// 4 waves/block; wave w owns bins w*12 .. w*12+12 (13 bins, 3 dups benign).
// Lane l covers channels 4l..4l+3 via half4 loads (8B/lane, full wave=256ch).
__global__ __launch_bounds__(256, 4) void riroi_main(
    const half_t* __restrict__ feat, const float* __restrict__ rois,
    const Geom* __restrict__ geom, float* __restrict__ out) {
  __shared__ alignas(16) float s_tr[64 * NBIN];  // 12.25 KB chunk (64 ch)

  const int r = blockIdx.x;
  const int t = threadIdx.x;
  const int w = t >> 6;
  const int l = t & 63;
  const int b0 = w * 12;

  const float theta = rois[(size_t)r * 6 + 5];  // uniform
  const float indf = theta * (8.0f / 6.2831853071795862f);
  const float ind0 = floorf(indf);
  const float lmix = indf - ind0;
  const int   ind  = ((int)ind0) & 7;
  const int   m    = (8 - ind) & 7;  // T[j] = B[(m+j)&7]

  const Geom* gp = geom + (size_t)r * NSAMP + b0 * 4;
  const char* fb = (const char*)feat;
  const int lane_off = l << 3;  // 8 B per lane (4 fp16 channels)

  float acc[WBINS][4];
#pragma unroll
  for (int i = 0; i < WBINS; ++i)
#pragma unroll
    for (int j = 0; j < 4; ++j) acc[i][j] = 0.f;

  // ---- gather: 13 bins x 4 subsamples x 4 taps, half4 per tap ----
#pragma unroll
  for (int bb = 0; bb < WBINS; ++bb) {
#pragma unroll
    for (int sub = 0; sub < 4; ++sub) {
      const Geom gg = gp[bb * 4 + sub];  // uniform -> s_load
#pragma unroll
      for (int k = 0; k < 4; ++k) {
        const int ok = __builtin_amdgcn_readfirstlane(gg.o[k]);
        const h4 v = *(const h4*)(fb + ok + lane_off);
        const float wk = gg.w[k];
#pragma unroll
        for (int j = 0; j < 4; ++j)
          acc[bb][j] += wk * (float)v[j];   // v_fma_mix_f32
      }
    }
  }

  // ---- orientation mix in-register (lane pair holds the 8-group) ----
  // B[i] = v[(4p+i)&7], p = l&1; out[4p+j] = lerp(B[(m+j)&7], B[(m+j+1)&7], lmix)
#define MIX_BODY(M)                                                        \
  {                                                                        \
    _Pragma("unroll")                                                      \
    for (int bb = 0; bb < WBINS; ++bb) {                                   \
      float B[8];                                                          \
      B[0] = acc[bb][0]; B[1] = acc[bb][1];                                \
      B[2] = acc[bb][2]; B[3] = acc[bb][3];                                \
      B[4] = __shfl_xor(acc[bb][0], 1, 64);                                \
      B[5] = __shfl_xor(acc[bb][1], 1, 64);                                \
      B[6] = __shfl_xor(acc[bb][2], 1, 64);                                \
      B[7] = __shfl_xor(acc[bb][3], 1, 64);                                \
      float tt[4];                                                         \
      _Pragma("unroll")                                                    \
      for (int j = 0; j < 4; ++j) {                                        \
        const float a0 = B[((M) + j) & 7];                                 \
        const float a1 = B[((M) + j + 1) & 7];                             \
        tt[j] = a0 + lmix * (a1 - a0);                                     \
      }                                                                    \
      acc[bb][0] = tt[0]; acc[bb][1] = tt[1];                              \
      acc[bb][2] = tt[2]; acc[bb][3] = tt[3];                              \
    }                                                                      \
  }
  switch (m) {
    case 0: MIX_BODY(0) break;
    case 1: MIX_BODY(1) break;
    case 2: MIX_BODY(2) break;
    case 3: MIX_BODY(3) break;
    case 4: MIX_BODY(4) break;
    case 5: MIX_BODY(5) break;
    case 6: MIX_BODY(6) break;
    case 7: MIX_BODY(7) break;
  }
#undef MIX_BODY

  // ---- store rounds: 64 channels at a time via LDS transpose ----
#pragma unroll
  for (int g = 0; g < 4; ++g) {
    if ((l >> 4) == g) {
      const int cl = (l & 15) * 4;  // local channel base within chunk
#pragma unroll
      for (int bb = 0; bb < WBINS; ++bb) {
        const int bin = b0 + bb;
        s_tr[(cl + 0) * NBIN + bin] = acc[bb][0];
        s_tr[(cl + 1) * NBIN + bin] = acc[bb][1];
        s_tr[(cl + 2) * NBIN + bin] = acc[bb][2];
        s_tr[(cl + 3) * NBIN + bin] = acc[bb][3];
      }
    }
    __syncthreads();
    const float4* s4 = (const float4*)s_tr;
    float4* d4 = (float4*)(out + ((size_t)r * NCH + g * 64) * NBIN);
    for (int i = t; i < 64 * NBIN / 4; i += 256) d4[i] = s4[i];
    __syncthreads();
  }
}

// ---------------- tier-2 fallback: LDS-geometry channels-last fp16 --------
__global__ __launch_bounds__(256) void riroi_cl_h(
    const half_t* __restrict__ feat, const float* __restrict__ rois,
    float* __restrict__ out) {
  __shared__ int4   s_off[NSAMP];
  __shared__ float4 s_w[NSAMP];
  __shared__ alignas(16) float s_tr2[64 * NBIN];

  const int r = blockIdx.x;
  const int c = threadIdx.x;
  const float* roi = rois + (size_t)r * 6;
  const int   b     = (int)roi[0];
  const float theta = roi[5];

  if (c < NSAMP) {
    const float cx = roi[1] * 0.25f;
    const float cy = roi[2] * 0.25f;
    const float rw = fmaxf(roi[3] * 0.25f, 1.0f);
    const float rh = fmaxf(roi[4] * 0.25f, 1.0f);
    const float bin_w = rw * (1.0f / OUTS);
    const float bin_h = rh * (1.0f / OUTS);
    const float ct = cosf(theta), st = sinf(theta);
    const float hbw = 0.5f * bin_w, hbh = 0.5f * bin_h;
    const float xoff = 0.25f * bin_w - 0.5f * rw;
    const float yoff = 0.25f * bin_h - 0.5f * rh;
    const int py = c / (2 * OUTS);
    const int px = c - py * (2 * OUTS);
    const float yy = (float)py * hbh + yoff;
    const float xx = (float)px * hbw + xoff;
    const float x = xx * ct + yy * st + cx;
    const float y = yy * ct - xx * st + cy;
    int4   o4 = {0, 0, 0, 0};
    float4 w4 = {0.f, 0.f, 0.f, 0.f};
    if (x > -1.0f && x < (float)FW && y > -1.0f && y < (float)FH) {
      float xc = fmaxf(x, 0.f), yc = fmaxf(y, 0.f);
      int x0 = (int)xc, y0 = (int)yc, x1, y1;
      float lx, ly;
      if (x0 >= FW - 1) { x0 = FW - 1; x1 = FW - 1; lx = 0.f; }
      else              { x1 = x0 + 1; lx = xc - (float)x0; }
      if (y0 >= FH - 1) { y0 = FH - 1; y1 = FH - 1; ly = 0.f; }
      else              { y1 = y0 + 1; ly = yc - (float)y0; }
      const float wx0 = 1.f - lx, wy0 = 1.f - ly;
      w4.x = wy0 * wx0; w4.y = wy0 * lx; w4.z = ly * wx0; w4.w = ly * lx;
      o4.x = (y0 * FW + x0) * NCH; o4.y = (y0 * FW + x1) * NCH;
      o4.z = (y1 * FW + x0) * NCH; o4.w = (y1 * FW + x1) * NCH;
    }
    s_off[c] = o4;
    s_w[c]   = w4;
  }
  __syncthreads();

  const half_t* fbb = feat + (size_t)b * (NCH * HW) + c;
  float acc[NBIN];
#pragma unroll
  for (int i = 0; i < NBIN; ++i) acc[i] = 0.f;
#pragma unroll
  for (int py = 0; py < 2 * OUTS; ++py) {
#pragma unroll
    for (int px = 0; px < 2 * OUTS; ++px) {
      const int s = py * (2 * OUTS) + px;
      const int bin = (py >> 1) * OUTS + (px >> 1);
      const int4   o = s_off[s];
      const float4 w = s_w[s];
      acc[bin] += w.x * (float)fbb[o.x] + w.y * (float)fbb[o.y]
                + w.z * (float)fbb[o.z] + w.w * (float)fbb[o.w];
    }
  }
#pragma unroll
  for (int i = 0; i < NBIN; ++i) acc[i] *= 0.25f;

  const float indf = (theta * 8.0f) / 6.2831853071795862f;
  const float ind0 = floorf(indf);
  const float l    = indf - ind0;
  const int   ind  = ((int)ind0) % NORI;
  const int   o    = c & 7;
  const int   lane = c & 63;
  const int srcLane  = (lane & 56) | ((o - ind + 8) & 7);
  const int srcLane2 = (lane & 56) | ((o - ind + 9) & 7);
#pragma unroll
  for (int i = 0; i < NBIN; ++i) {
    const float v  = acc[i];
    const float vs = __shfl(v, srcLane, 64);
    const float vp = __shfl(v, srcLane2, 64);
    acc[i] = (1.f - l) * vs + l * vp;
  }
  const int grp = c >> 6;
#pragma unroll
  for (int g = 0; g < 4; ++g) {
    if (grp == g) {
#pragma unroll
      for (int i = 0; i < NBIN; ++i) s_tr2[(c & 63) * NBIN + i] = acc[i];
    }
    __syncthreads();
    const float4* s4 = (const float4*)s_tr2;
    float4* d4 = (float4*)(out + ((size_t)r * NCH + g * 64) * NBIN);
#pragma unroll
    for (int i = 0; i < 4; ++i) {
      int idx = c + i * 256;
      if (idx < 64 * NBIN / 4) d4[idx] = s4[idx];
    }
    __syncthreads();
  }
}

// ---------------- tier-3 fallback: fp32 NCHW direct ----------------------
__global__ __launch_bounds__(256) void riroi_cf(
    const float* __restrict__ feat, const float* __restrict__ rois,
    float* __restrict__ out) {
  const int r = blockIdx.x;
  const int c = threadIdx.x;
  const float* roi = rois + (size_t)r * 6;
  const int   b     = (int)roi[0];
  const float cx    = roi[1] * 0.25f;
  const float cy    = roi[2] * 0.25f;
  const float rw    = fmaxf(roi[3] * 0.25f, 1.0f);
  const float rh    = fmaxf(roi[4] * 0.25f, 1.0f);
  const float theta = roi[5];
  const float bin_w = rw * (1.0f / OUTS), bin_h = rh * (1.0f / OUTS);
  const float ct = cosf(theta), st = sinf(theta);
  const float hbw = 0.5f * bin_w, hbh = 0.5f * bin_h;
  const float xoff = 0.25f * bin_w - 0.5f * rw;
  const float yoff = 0.25f * bin_h - 0.5f * rh;
  const float* fb = feat + ((size_t)b * NCH + c) * HW;
  float acc[NBIN];
#pragma unroll
  for (int i = 0; i < NBIN; ++i) acc[i] = 0.f;
  for (int py = 0; py < 2 * OUTS; ++py) {
    const float yy = (float)py * hbh + yoff;
    for (int px = 0; px < 2 * OUTS; ++px) {
      const float xx = (float)px * hbw + xoff;
      const float x = xx * ct + yy * st + cx;
      const float y = yy * ct - xx * st + cy;
      if (x > -1.0f && x < (float)FW && y > -1.0f && y < (float)FH) {
        float xc = fmaxf(x, 0.f), yc = fmaxf(y, 0.f);
        int x0 = (int)xc, y0 = (int)yc, x1, y1;
        float lx, ly;
        if (x0 >= FW - 1) { x0 = FW - 1; x1 = FW - 1; lx = 0.f; }
        else              { x1 = x0 + 1; lx = xc - (float)x0; }
        if (y0 >= FH - 1) { y0 = FH - 1; y1 = FH - 1; ly = 0.f; }
        else              { y1 = y0 + 1; ly = yc - (float)y0; }
        const float wx0 = 1.f - lx, wy0 = 1.f - ly;
        acc[(py >> 1) * OUTS + (px >> 1)] +=
            (wy0 * wx0) * fb[y0 * FW + x0] + (wy0 * lx) * fb[y0 * FW + x1]
          + (ly * wx0) * fb[y1 * FW + x0] + (ly * lx) * fb[y1 * FW + x1];
      }
    }
  }
#pragma unroll
  for (int i = 0; i < NBIN; ++i) acc[i] *= 0.25f;
  const float indf = (theta * 8.0f) / 6.2831853071795862f;
  const float ind0 = floorf(indf);
  const float l    = indf - ind0;
  const int   ind  = ((int)ind0) % NORI;
  const int   o    = c & 7;
  const int   lane = c & 63;
  const int srcLane  = (lane & 56) | ((o - ind + 8) & 7);
  const int srcLane2 = (lane & 56) | ((o - ind + 9) & 7);
  float* op = out + ((size_t)r * NCH + c) * NBIN;
#pragma unroll
  for (int i = 0; i < NBIN; ++i) {
    const float v  = acc[i];
    const float vs = __shfl(v, srcLane, 64);
    const float vp = __shfl(v, srcLane2, 64);
    op[i] = (1.f - l) * vs + l * vp;
  }
}

extern "C" void kernel_launch(void* const* d_in, const int* in_sizes, int n_in,
                              void* d_out, int out_size, void* d_ws, size_t ws_size,
                              hipStream_t stream) {
  const float* feat = (const float*)d_in[0];
  const float* rois = (const float*)d_in[1];
  float* out = (float*)d_out;
  const int R = in_sizes[1] / 6;
  const int N = in_sizes[0] / (NCH * HW);

  const size_t geom_bytes = (size_t)R * NSAMP * sizeof(Geom);
  const size_t feat_bytes = (size_t)N * HW * NCH * sizeof(half_t);

  if (ws_size >= geom_bytes + feat_bytes) {
    Geom*   g  = (Geom*)d_ws;
    half_t* ft = (half_t*)((char*)d_ws + geom_bytes);
    dim3 tg(HW / 64, NCH / 64, N);
    transpose_nchw_nhwc_h<<<tg, 256, 0, stream>>>(feat, ft);
    const int total = R * NSAMP;
    geom_kernel<<<(total + 255) / 256, 256, 0, stream>>>(rois, g, total);
    riroi_main<<<R, 256, 0, stream>>>(ft, rois, g, out);
  } else if (ws_size >= feat_bytes) {
    half_t* ft = (half_t*)d_ws;
    dim3 tg(HW / 64, NCH / 64, N);
    transpose_nchw_nhwc_h<<<tg, 256, 0, stream>>>(feat, ft);
    riroi_cl_h<<<R, 256, 0, stream>>>(ft, rois, out);
  } else {
    riroi_cf<<<R, 256, 0, stream>>>(feat, rois, out);
  }
}

// Round 6
// 196.726 us; speedup vs baseline: 2.2170x; 2.2170x over previous
//
#include <hip/hip_runtime.h>

typedef _Float16 half_t;
typedef _Float16 h4 __attribute__((ext_vector_type(4)));

#define OUTS 7
#define NORI 8
#define NCH  256
#define FH   128
#define FW   128
#define HW   (FH * FW)
#define NSAMP (2 * OUTS * 2 * OUTS)  // 196 = 49 bins * 4 subsamples
#define NBIN  (OUTS * OUTS)          // 49
#define WBINS 7                      // bins per wave (8 waves, starts 0,6,12,...,42)

struct __align__(32) Geom { int o[4]; float w[4]; };

// ---------------- transpose [N,C,H,W] f32 -> [N,H,W,C] f16 ----------------
__global__ __launch_bounds__(256) void transpose_nchw_nhwc_h(
    const float* __restrict__ in, half_t* __restrict__ out) {
  __shared__ float tile[64][65];
  const int b  = blockIdx.z;
  const int p0 = blockIdx.x * 64;
  const int c0 = blockIdx.y * 64;
  const int tx = threadIdx.x & 63;
  const int ty = threadIdx.x >> 6;

  const float* src = in + ((size_t)b * NCH + c0) * HW + p0;
#pragma unroll
  for (int i = 0; i < 16; ++i) {
    int c = ty + i * 4;
    tile[c][tx] = src[(size_t)c * HW + tx];
  }
  __syncthreads();
  half_t* dst = out + ((size_t)b * HW + p0) * NCH + c0;
#pragma unroll
  for (int i = 0; i < 16; ++i) {
    int p = ty + i * 4;
    dst[(size_t)p * NCH + tx] = (half_t)tile[tx][p];
  }
}

// ---------------- geometry precompute: one (roi, sample) per thread ------
// g[r*196 + bin*4 + sub]; byte offsets (batch folded, <<9 = *NCH*2B); weights
// pre-scaled by 0.25 (2x2 sample mean).
__global__ __launch_bounds__(256) void geom_kernel(
    const float* __restrict__ rois, Geom* __restrict__ g, int total) {
  const int gid = blockIdx.x * 256 + threadIdx.x;
  if (gid >= total) return;
  const int r   = gid / NSAMP;
  const int q   = gid - r * NSAMP;
  const int bin = q >> 2;
  const int sub = q & 3;
  const int by = bin / OUTS, bx = bin - by * OUTS;
  const int py = by * 2 + (sub >> 1);
  const int px = bx * 2 + (sub & 1);

  const float* roi = rois + (size_t)r * 6;
  const int   b     = (int)roi[0];
  const float cx    = roi[1] * 0.25f;
  const float cy    = roi[2] * 0.25f;
  const float rw    = fmaxf(roi[3] * 0.25f, 1.0f);
  const float rh    = fmaxf(roi[4] * 0.25f, 1.0f);
  const float theta = roi[5];
  const float bin_w = rw * (1.0f / OUTS);
  const float bin_h = rh * (1.0f / OUTS);
  const float ct = cosf(theta), st = sinf(theta);
  const float hbw = 0.5f * bin_w, hbh = 0.5f * bin_h;
  const float xoff = 0.25f * bin_w - 0.5f * rw;
  const float yoff = 0.25f * bin_h - 0.5f * rh;

  const float yy = (float)py * hbh + yoff;
  const float xx = (float)px * hbw + xoff;
  const float x = xx * ct + yy * st + cx;
  const float y = yy * ct - xx * st + cy;

  Geom gg;
  gg.o[0] = gg.o[1] = gg.o[2] = gg.o[3] = 0;
  gg.w[0] = gg.w[1] = gg.w[2] = gg.w[3] = 0.f;
  if (x > -1.0f && x < (float)FW && y > -1.0f && y < (float)FH) {
    float xc = fmaxf(x, 0.f);
    float yc = fmaxf(y, 0.f);
    int x0 = (int)xc;
    int y0 = (int)yc;
    int x1, y1;
    float lx, ly;
    if (x0 >= FW - 1) { x0 = FW - 1; x1 = FW - 1; lx = 0.f; }
    else              { x1 = x0 + 1; lx = xc - (float)x0; }
    if (y0 >= FH - 1) { y0 = FH - 1; y1 = FH - 1; ly = 0.f; }
    else              { y1 = y0 + 1; ly = yc - (float)y0; }
    const float wx0 = 1.f - lx, wy0 = 1.f - ly;
    gg.w[0] = 0.25f * wy0 * wx0; gg.w[1] = 0.25f * wy0 * lx;
    gg.w[2] = 0.25f * ly  * wx0; gg.w[3] = 0.25f * ly  * lx;
    const int base = b * HW;
    gg.o[0] = (base + y0 * FW + x0) << 9; gg.o[1] = (base + y0 * FW + x1) << 9;
    gg.o[2] = (base + y1 * FW + x0) << 9; gg.o[3] = (base + y1 * FW + x1) << 9;
  }
  g[gid] = gg;
}

// ---------------- main kernel ---------------------------------------------
// 512 threads = 8 waves; wave w owns bins w*6 .. w*6+6 (7 bins, boundary bins
// duplicated across waves -- identical values, benign). Lane l covers channels
// 4l..4l+3 via half4 loads (8 B/lane, one wave = all 256 channels).
__global__ __launch_bounds__(512) void riroi_main(
    const half_t* __restrict__ feat, const float* __restrict__ rois,
    const Geom* __restrict__ geom, float* __restrict__ out) {
  __shared__ alignas(16) float s_tr[NCH * NBIN];  // 49 KB

  const int r = blockIdx.x;
  const int t = threadIdx.x;
  const int w = t >> 6;
  const int l = t & 63;
  const int b0 = w * 6;

  const float theta = rois[(size_t)r * 6 + 5];  // uniform
  const float indf = theta * (8.0f / 6.2831853071795862f);
  const float ind0 = floorf(indf);
  const float lmix = indf - ind0;
  const int   ind  = ((int)ind0) & 7;
  const int   m    = (8 - ind) & 7;  // T[j] = B[(m+j)&7]

  const int rb0 = __builtin_amdgcn_readfirstlane(b0);
  const Geom* gp = geom + (size_t)r * NSAMP + rb0 * 4;  // uniform -> s_load
  const char* fb = (const char*)feat;
  const int lane_off = l << 3;  // 8 B per lane (4 fp16 channels)

  float acc[WBINS][4];
#pragma unroll
  for (int i = 0; i < WBINS; ++i)
#pragma unroll
    for (int j = 0; j < 4; ++j) acc[i][j] = 0.f;

  // ---- gather: 7 bins x 4 subsamples x 4 taps, half4 per tap ----
#pragma unroll
  for (int bb = 0; bb < WBINS; ++bb) {
#pragma unroll
    for (int sub = 0; sub < 4; ++sub) {
      const Geom gg = gp[bb * 4 + sub];  // s_load_dwordx8
#pragma unroll
      for (int k = 0; k < 4; ++k) {
        const int ok = __builtin_amdgcn_readfirstlane(gg.o[k]);
        const h4 v = *(const h4*)(fb + ok + lane_off);
        const float wk = gg.w[k];
#pragma unroll
        for (int j = 0; j < 4; ++j)
          acc[bb][j] += wk * (float)v[j];   // v_fma_mix_f32
      }
    }
  }

  // ---- orientation mix in-register (lane pair holds the 8-group) ----
  // B[i] = v[(4p+i)&7], p = l&1; out[4p+j] = lerp(B[(m+j)&7], B[(m+j+1)&7], lmix)
#define MIX_BODY(M)                                                        \
  {                                                                        \
    _Pragma("unroll")                                                      \
    for (int bb = 0; bb < WBINS; ++bb) {                                   \
      float B[8];                                                          \
      B[0] = acc[bb][0]; B[1] = acc[bb][1];                                \
      B[2] = acc[bb][2]; B[3] = acc[bb][3];                                \
      B[4] = __shfl_xor(acc[bb][0], 1, 64);                                \
      B[5] = __shfl_xor(acc[bb][1], 1, 64);                                \
      B[6] = __shfl_xor(acc[bb][2], 1, 64);                                \
      B[7] = __shfl_xor(acc[bb][3], 1, 64);                                \
      float tt[4];                                                         \
      _Pragma("unroll")                                                    \
      for (int j = 0; j < 4; ++j) {                                        \
        const float a0 = B[((M) + j) & 7];                                 \
        const float a1 = B[((M) + j + 1) & 7];                             \
        tt[j] = a0 + lmix * (a1 - a0);                                     \
      }                                                                    \
      acc[bb][0] = tt[0]; acc[bb][1] = tt[1];                              \
      acc[bb][2] = tt[2]; acc[bb][3] = tt[3];                              \
    }                                                                      \
  }
  switch (m) {
    case 0: MIX_BODY(0) break;
    case 1: MIX_BODY(1) break;
    case 2: MIX_BODY(2) break;
    case 3: MIX_BODY(3) break;
    case 4: MIX_BODY(4) break;
    case 5: MIX_BODY(5) break;
    case 6: MIX_BODY(6) break;
    case 7: MIX_BODY(7) break;
  }
#undef MIX_BODY

  // ---- stage [ch][bin] in LDS (2-way write conflicts = free), then ----
  // ---- one fully-coalesced float4 copy of the whole roi block.      ----
#pragma unroll
  for (int bb = 0; bb < WBINS; ++bb) {
    const int bin = b0 + bb;
#pragma unroll
    for (int j = 0; j < 4; ++j)
      s_tr[(4 * l + j) * NBIN + bin] = acc[bb][j];
  }
  __syncthreads();

  const float4* s4 = (const float4*)s_tr;
  float4* d4 = (float4*)(out + (size_t)r * (NCH * NBIN));
  for (int i = t; i < NCH * NBIN / 4; i += 512) d4[i] = s4[i];
}

// ---------------- tier-2 fallback: LDS-geometry channels-last fp16 --------
__global__ __launch_bounds__(256) void riroi_cl_h(
    const half_t* __restrict__ feat, const float* __restrict__ rois,
    float* __restrict__ out) {
  __shared__ int4   s_off[NSAMP];
  __shared__ float4 s_w[NSAMP];
  __shared__ alignas(16) float s_tr2[64 * NBIN];

  const int r = blockIdx.x;
  const int c = threadIdx.x;
  const float* roi = rois + (size_t)r * 6;
  const int   b     = (int)roi[0];
  const float theta = roi[5];

  if (c < NSAMP) {
    const float cx = roi[1] * 0.25f;
    const float cy = roi[2] * 0.25f;
    const float rw = fmaxf(roi[3] * 0.25f, 1.0f);
    const float rh = fmaxf(roi[4] * 0.25f, 1.0f);
    const float bin_w = rw * (1.0f / OUTS);
    const float bin_h = rh * (1.0f / OUTS);
    const float ct = cosf(theta), st = sinf(theta);
    const float hbw = 0.5f * bin_w, hbh = 0.5f * bin_h;
    const float xoff = 0.25f * bin_w - 0.5f * rw;
    const float yoff = 0.25f * bin_h - 0.5f * rh;
    const int py = c / (2 * OUTS);
    const int px = c - py * (2 * OUTS);
    const float yy = (float)py * hbh + yoff;
    const float xx = (float)px * hbw + xoff;
    const float x = xx * ct + yy * st + cx;
    const float y = yy * ct - xx * st + cy;
    int4   o4 = {0, 0, 0, 0};
    float4 w4 = {0.f, 0.f, 0.f, 0.f};
    if (x > -1.0f && x < (float)FW && y > -1.0f && y < (float)FH) {
      float xc = fmaxf(x, 0.f), yc = fmaxf(y, 0.f);
      int x0 = (int)xc, y0 = (int)yc, x1, y1;
      float lx, ly;
      if (x0 >= FW - 1) { x0 = FW - 1; x1 = FW - 1; lx = 0.f; }
      else              { x1 = x0 + 1; lx = xc - (float)x0; }
      if (y0 >= FH - 1) { y0 = FH - 1; y1 = FH - 1; ly = 0.f; }
      else              { y1 = y0 + 1; ly = yc - (float)y0; }
      const float wx0 = 1.f - lx, wy0 = 1.f - ly;
      w4.x = wy0 * wx0; w4.y = wy0 * lx; w4.z = ly * wx0; w4.w = ly * lx;
      o4.x = (y0 * FW + x0) * NCH; o4.y = (y0 * FW + x1) * NCH;
      o4.z = (y1 * FW + x0) * NCH; o4.w = (y1 * FW + x1) * NCH;
    }
    s_off[c] = o4;
    s_w[c]   = w4;
  }
  __syncthreads();

  const half_t* fbb = feat + (size_t)b * (NCH * HW) + c;
  float acc[NBIN];
#pragma unroll
  for (int i = 0; i < NBIN; ++i) acc[i] = 0.f;
#pragma unroll
  for (int py = 0; py < 2 * OUTS; ++py) {
#pragma unroll
    for (int px = 0; px < 2 * OUTS; ++px) {
      const int s = py * (2 * OUTS) + px;
      const int bin = (py >> 1) * OUTS + (px >> 1);
      const int4   o = s_off[s];
      const float4 w = s_w[s];
      acc[bin] += w.x * (float)fbb[o.x] + w.y * (float)fbb[o.y]
                + w.z * (float)fbb[o.z] + w.w * (float)fbb[o.w];
    }
  }
#pragma unroll
  for (int i = 0; i < NBIN; ++i) acc[i] *= 0.25f;

  const float indf = (theta * 8.0f) / 6.2831853071795862f;
  const float ind0 = floorf(indf);
  const float l    = indf - ind0;
  const int   ind  = ((int)ind0) % NORI;
  const int   o    = c & 7;
  const int   lane = c & 63;
  const int srcLane  = (lane & 56) | ((o - ind + 8) & 7);
  const int srcLane2 = (lane & 56) | ((o - ind + 9) & 7);
#pragma unroll
  for (int i = 0; i < NBIN; ++i) {
    const float v  = acc[i];
    const float vs = __shfl(v, srcLane, 64);
    const float vp = __shfl(v, srcLane2, 64);
    acc[i] = (1.f - l) * vs + l * vp;
  }
  const int grp = c >> 6;
#pragma unroll
  for (int g = 0; g < 4; ++g) {
    if (grp == g) {
#pragma unroll
      for (int i = 0; i < NBIN; ++i) s_tr2[(c & 63) * NBIN + i] = acc[i];
    }
    __syncthreads();
    const float4* s4 = (const float4*)s_tr2;
    float4* d4 = (float4*)(out + ((size_t)r * NCH + g * 64) * NBIN);
#pragma unroll
    for (int i = 0; i < 4; ++i) {
      int idx = c + i * 256;
      if (idx < 64 * NBIN / 4) d4[idx] = s4[idx];
    }
    __syncthreads();
  }
}

// ---------------- tier-3 fallback: fp32 NCHW direct ----------------------
__global__ __launch_bounds__(256) void riroi_cf(
    const float* __restrict__ feat, const float* __restrict__ rois,
    float* __restrict__ out) {
  const int r = blockIdx.x;
  const int c = threadIdx.x;
  const float* roi = rois + (size_t)r * 6;
  const int   b     = (int)roi[0];
  const float cx    = roi[1] * 0.25f;
  const float cy    = roi[2] * 0.25f;
  const float rw    = fmaxf(roi[3] * 0.25f, 1.0f);
  const float rh    = fmaxf(roi[4] * 0.25f, 1.0f);
  const float theta = roi[5];
  const float bin_w = rw * (1.0f / OUTS), bin_h = rh * (1.0f / OUTS);
  const float ct = cosf(theta), st = sinf(theta);
  const float hbw = 0.5f * bin_w, hbh = 0.5f * bin_h;
  const float xoff = 0.25f * bin_w - 0.5f * rw;
  const float yoff = 0.25f * bin_h - 0.5f * rh;
  const float* fb = feat + ((size_t)b * NCH + c) * HW;
  float acc[NBIN];
#pragma unroll
  for (int i = 0; i < NBIN; ++i) acc[i] = 0.f;
  for (int py = 0; py < 2 * OUTS; ++py) {
    const float yy = (float)py * hbh + yoff;
    for (int px = 0; px < 2 * OUTS; ++px) {
      const float xx = (float)px * hbw + xoff;
      const float x = xx * ct + yy * st + cx;
      const float y = yy * ct - xx * st + cy;
      if (x > -1.0f && x < (float)FW && y > -1.0f && y < (float)FH) {
        float xc = fmaxf(x, 0.f), yc = fmaxf(y, 0.f);
        int x0 = (int)xc, y0 = (int)yc, x1, y1;
        float lx, ly;
        if (x0 >= FW - 1) { x0 = FW - 1; x1 = FW - 1; lx = 0.f; }
        else              { x1 = x0 + 1; lx = xc - (float)x0; }
        if (y0 >= FH - 1) { y0 = FH - 1; y1 = FH - 1; ly = 0.f; }
        else              { y1 = y0 + 1; ly = yc - (float)y0; }
        const float wx0 = 1.f - lx, wy0 = 1.f - ly;
        acc[(py >> 1) * OUTS + (px >> 1)] +=
            (wy0 * wx0) * fb[y0 * FW + x0] + (wy0 * lx) * fb[y0 * FW + x1]
          + (ly * wx0) * fb[y1 * FW + x0] + (ly * lx) * fb[y1 * FW + x1];
      }
    }
  }
#pragma unroll
  for (int i = 0; i < NBIN; ++i) acc[i] *= 0.25f;
  const float indf = (theta * 8.0f) / 6.2831853071795862f;
  const float ind0 = floorf(indf);
  const float l    = indf - ind0;
  const int   ind  = ((int)ind0) % NORI;
  const int   o    = c & 7;
  const int   lane = c & 63;
  const int srcLane  = (lane & 56) | ((o - ind + 8) & 7);
  const int srcLane2 = (lane & 56) | ((o - ind + 9) & 7);
  float* op = out + ((size_t)r * NCH + c) * NBIN;
#pragma unroll
  for (int i = 0; i < NBIN; ++i) {
    const float v  = acc[i];
    const float vs = __shfl(v, srcLane, 64);
    const float vp = __shfl(v, srcLane2, 64);
    op[i] = (1.f - l) * vs + l * vp;
  }
}

extern "C" void kernel_launch(void* const* d_in, const int* in_sizes, int n_in,
                              void* d_out, int out_size, void* d_ws, size_t ws_size,
                              hipStream_t stream) {
  const float* feat = (const float*)d_in[0];
  const float* rois = (const float*)d_in[1];
  float* out = (float*)d_out;
  const int R = in_sizes[1] / 6;
  const int N = in_sizes[0] / (NCH * HW);

  const size_t geom_bytes = (size_t)R * NSAMP * sizeof(Geom);
  const size_t feat_bytes = (size_t)N * HW * NCH * sizeof(half_t);

  if (ws_size >= geom_bytes + feat_bytes) {
    Geom*   g  = (Geom*)d_ws;
    half_t* ft = (half_t*)((char*)d_ws + geom_bytes);
    dim3 tg(HW / 64, NCH / 64, N);
    transpose_nchw_nhwc_h<<<tg, 256, 0, stream>>>(feat, ft);
    const int total = R * NSAMP;
    geom_kernel<<<(total + 255) / 256, 256, 0, stream>>>(rois, g, total);
    riroi_main<<<R, 512, 0, stream>>>(ft, rois, g, out);
  } else if (ws_size >= feat_bytes) {
    half_t* ft = (half_t*)d_ws;
    dim3 tg(HW / 64, NCH / 64, N);
    transpose_nchw_nhwc_h<<<tg, 256, 0, stream>>>(feat, ft);
    riroi_cl_h<<<R, 256, 0, stream>>>(ft, rois, out);
  } else {
    riroi_cf<<<R, 256, 0, stream>>>(feat, rois, out);
  }
}

// Round 8
// 196.211 us; speedup vs baseline: 2.2228x; 1.0026x over previous
//
#include <hip/hip_runtime.h>

typedef _Float16 half_t;
typedef _Float16 h4 __attribute__((ext_vector_type(4)));
typedef int   v4i __attribute__((ext_vector_type(4)));
typedef float v4f __attribute__((ext_vector_type(4)));

#define OUTS 7
#define NORI 8
#define NCH  256
#define FH   128
#define FW   128
#define HW   (FH * FW)
#define NSAMP (2 * OUTS * 2 * OUTS)  // 196 = 49 bins * 4 subsamples
#define NBIN  (OUTS * OUTS)          // 49
#define WBINS 7                      // bins per wave (8 waves, starts 0,6,...,42)

struct __align__(32) Geom { int o[4]; float w[4]; };

// ---------------- transpose [N,C,H,W] f32 -> [N,H,W,C] f16 ----------------
__global__ __launch_bounds__(256) void transpose_nchw_nhwc_h(
    const float* __restrict__ in, half_t* __restrict__ out) {
  __shared__ float tile[64][65];
  const int b  = blockIdx.z;
  const int p0 = blockIdx.x * 64;
  const int c0 = blockIdx.y * 64;
  const int tx = threadIdx.x & 63;
  const int ty = threadIdx.x >> 6;

  const float* src = in + ((size_t)b * NCH + c0) * HW + p0;
#pragma unroll
  for (int i = 0; i < 16; ++i) {
    int c = ty + i * 4;
    tile[c][tx] = src[(size_t)c * HW + tx];
  }
  __syncthreads();
  half_t* dst = out + ((size_t)b * HW + p0) * NCH + c0;
#pragma unroll
  for (int i = 0; i < 16; ++i) {
    int p = ty + i * 4;
    dst[(size_t)p * NCH + tx] = (half_t)tile[tx][p];
  }
}

// ---------------- geometry precompute: one (roi, sample) per thread ------
// g[r*196 + bin*4 + sub]; byte offsets (batch folded, <<9 = *NCH*2B); weights
// pre-scaled by 0.25 (2x2 sample mean). Nontemporal stores: don't evict the
// feature set from L2 (features must stay hot for the main kernel's gathers).
__global__ __launch_bounds__(256) void geom_kernel(
    const float* __restrict__ rois, Geom* __restrict__ g, int total) {
  const int gid = blockIdx.x * 256 + threadIdx.x;
  if (gid >= total) return;
  const int r   = gid / NSAMP;
  const int q   = gid - r * NSAMP;
  const int bin = q >> 2;
  const int sub = q & 3;
  const int by = bin / OUTS, bx = bin - by * OUTS;
  const int py = by * 2 + (sub >> 1);
  const int px = bx * 2 + (sub & 1);

  const float* roi = rois + (size_t)r * 6;
  const int   b     = (int)roi[0];
  const float cx    = roi[1] * 0.25f;
  const float cy    = roi[2] * 0.25f;
  const float rw    = fmaxf(roi[3] * 0.25f, 1.0f);
  const float rh    = fmaxf(roi[4] * 0.25f, 1.0f);
  const float theta = roi[5];
  const float bin_w = rw * (1.0f / OUTS);
  const float bin_h = rh * (1.0f / OUTS);
  const float ct = cosf(theta), st = sinf(theta);
  const float hbw = 0.5f * bin_w, hbh = 0.5f * bin_h;
  const float xoff = 0.25f * bin_w - 0.5f * rw;
  const float yoff = 0.25f * bin_h - 0.5f * rh;

  const float yy = (float)py * hbh + yoff;
  const float xx = (float)px * hbw + xoff;
  const float x = xx * ct + yy * st + cx;
  const float y = yy * ct - xx * st + cy;

  v4i oo = {0, 0, 0, 0};
  v4f ww = {0.f, 0.f, 0.f, 0.f};
  if (x > -1.0f && x < (float)FW && y > -1.0f && y < (float)FH) {
    float xc = fmaxf(x, 0.f);
    float yc = fmaxf(y, 0.f);
    int x0 = (int)xc;
    int y0 = (int)yc;
    int x1, y1;
    float lx, ly;
    if (x0 >= FW - 1) { x0 = FW - 1; x1 = FW - 1; lx = 0.f; }
    else              { x1 = x0 + 1; lx = xc - (float)x0; }
    if (y0 >= FH - 1) { y0 = FH - 1; y1 = FH - 1; ly = 0.f; }
    else              { y1 = y0 + 1; ly = yc - (float)y0; }
    const float wx0 = 1.f - lx, wy0 = 1.f - ly;
    ww.x = 0.25f * wy0 * wx0; ww.y = 0.25f * wy0 * lx;
    ww.z = 0.25f * ly  * wx0; ww.w = 0.25f * ly  * lx;
    const int base = b * HW;
    oo.x = (base + y0 * FW + x0) << 9; oo.y = (base + y0 * FW + x1) << 9;
    oo.z = (base + y1 * FW + x0) << 9; oo.w = (base + y1 * FW + x1) << 9;
  }
  v4i* dst = (v4i*)&g[gid];
  __builtin_nontemporal_store(oo, dst);
  __builtin_nontemporal_store(*(v4i*)&ww, dst + 1);
}

// ---------------- main kernel ---------------------------------------------
// 512 threads = 8 waves; wave w owns bins w*6 .. w*6+6 (boundary bins computed
// twice with identical values -- benign). Lane l covers channels 4l..4l+3 via
// half4 loads. Per bin-half: 8 loads issued back-to-back (deep vmcnt batch),
// then 32 FMAs. Output staged in 2 channel-rounds of 25 KB LDS, nt-stored.
__global__ __launch_bounds__(512) void riroi_main(
    const half_t* __restrict__ feat, const float* __restrict__ rois,
    const Geom* __restrict__ geom, float* __restrict__ out) {
  __shared__ alignas(16) float s_tr[128 * NBIN];  // 25088 B

  const int r = blockIdx.x;
  const int t = threadIdx.x;
  const int w = t >> 6;
  const int l = t & 63;
  const int b0 = w * 6;

  const float theta = rois[(size_t)r * 6 + 5];  // uniform
  const float indf = theta * (8.0f / 6.2831853071795862f);
  const float ind0 = floorf(indf);
  const float lmix = indf - ind0;
  const int   ind  = ((int)ind0) & 7;
  const int   m    = (8 - ind) & 7;  // T[j] = B[(m+j)&7]

  const int rb0 = __builtin_amdgcn_readfirstlane(b0);
  const Geom* gp = geom + (size_t)r * NSAMP + rb0 * 4;  // uniform -> s_load
  const char* fb = (const char*)feat;
  const int lane_off = l << 3;  // 8 B per lane (4 fp16 channels)

  float acc[WBINS][4];
#pragma unroll
  for (int i = 0; i < WBINS; ++i)
#pragma unroll
    for (int j = 0; j < 4; ++j) acc[i][j] = 0.f;

  // ---- gather: per bin, 2 halves of {2 Geoms -> 8 batched loads, 32 FMA} ----
#pragma unroll
  for (int bb = 0; bb < WBINS; ++bb) {
#pragma unroll
    for (int half = 0; half < 2; ++half) {
      const Geom ga = gp[bb * 4 + half * 2 + 0];  // s_load_dwordx8
      const Geom gb = gp[bb * 4 + half * 2 + 1];
      h4 va[4], vb[4];
#pragma unroll
      for (int k = 0; k < 4; ++k)
        va[k] = *(const h4*)(fb + __builtin_amdgcn_readfirstlane(ga.o[k]) + lane_off);
#pragma unroll
      for (int k = 0; k < 4; ++k)
        vb[k] = *(const h4*)(fb + __builtin_amdgcn_readfirstlane(gb.o[k]) + lane_off);
#pragma unroll
      for (int k = 0; k < 4; ++k)
#pragma unroll
        for (int j = 0; j < 4; ++j)
          acc[bb][j] += ga.w[k] * (float)va[k][j];
#pragma unroll
      for (int k = 0; k < 4; ++k)
#pragma unroll
        for (int j = 0; j < 4; ++j)
          acc[bb][j] += gb.w[k] * (float)vb[k][j];
    }
  }

  // ---- orientation mix in-register (lane pair holds the 8-group) ----
#define MIX_BODY(M)                                                        \
  {                                                                        \
    _Pragma("unroll")                                                      \
    for (int bb = 0; bb < WBINS; ++bb) {                                   \
      float B[8];                                                          \
      B[0] = acc[bb][0]; B[1] = acc[bb][1];                                \
      B[2] = acc[bb][2]; B[3] = acc[bb][3];                                \
      B[4] = __shfl_xor(acc[bb][0], 1, 64);                                \
      B[5] = __shfl_xor(acc[bb][1], 1, 64);                                \
      B[6] = __shfl_xor(acc[bb][2], 1, 64);                                \
      B[7] = __shfl_xor(acc[bb][3], 1, 64);                                \
      float tt[4];                                                         \
      _Pragma("unroll")                                                    \
      for (int j = 0; j < 4; ++j) {                                        \
        const float a0 = B[((M) + j) & 7];                                 \
        const float a1 = B[((M) + j + 1) & 7];                             \
        tt[j] = a0 + lmix * (a1 - a0);                                     \
      }                                                                    \
      acc[bb][0] = tt[0]; acc[bb][1] = tt[1];                              \
      acc[bb][2] = tt[2]; acc[bb][3] = tt[3];                              \
    }                                                                      \
  }
  switch (m) {
    case 0: MIX_BODY(0) break;
    case 1: MIX_BODY(1) break;
    case 2: MIX_BODY(2) break;
    case 3: MIX_BODY(3) break;
    case 4: MIX_BODY(4) break;
    case 5: MIX_BODY(5) break;
    case 6: MIX_BODY(6) break;
    case 7: MIX_BODY(7) break;
  }
#undef MIX_BODY

  // ---- 2 channel-rounds: stage [128ch][49bin] in LDS, nt-copy coalesced ----
#pragma unroll
  for (int rnd = 0; rnd < 2; ++rnd) {
    if ((l >> 5) == rnd) {
      const int cl = (l & 31) * 4;  // local channel base 0..124
#pragma unroll
      for (int bb = 0; bb < WBINS; ++bb) {
        const int bin = b0 + bb;
#pragma unroll
        for (int j = 0; j < 4; ++j)
          s_tr[(cl + j) * NBIN + bin] = acc[bb][j];
      }
    }
    __syncthreads();
    const v4f* s4 = (const v4f*)s_tr;
    v4f* d4 = (v4f*)(out + (size_t)r * (NCH * NBIN) + rnd * (128 * NBIN));
    for (int i = t; i < 128 * NBIN / 4; i += 512)
      __builtin_nontemporal_store(s4[i], d4 + i);
    __syncthreads();
  }
}

// ---------------- tier-2 fallback: LDS-geometry channels-last fp16 --------
__global__ __launch_bounds__(256) void riroi_cl_h(
    const half_t* __restrict__ feat, const float* __restrict__ rois,
    float* __restrict__ out) {
  __shared__ int4   s_off[NSAMP];
  __shared__ float4 s_w[NSAMP];
  __shared__ alignas(16) float s_tr2[64 * NBIN];

  const int r = blockIdx.x;
  const int c = threadIdx.x;
  const float* roi = rois + (size_t)r * 6;
  const int   b     = (int)roi[0];
  const float theta = roi[5];

  if (c < NSAMP) {
    const float cx = roi[1] * 0.25f;
    const float cy = roi[2] * 0.25f;
    const float rw = fmaxf(roi[3] * 0.25f, 1.0f);
    const float rh = fmaxf(roi[4] * 0.25f, 1.0f);
    const float bin_w = rw * (1.0f / OUTS);
    const float bin_h = rh * (1.0f / OUTS);
    const float ct = cosf(theta), st = sinf(theta);
    const float hbw = 0.5f * bin_w, hbh = 0.5f * bin_h;
    const float xoff = 0.25f * bin_w - 0.5f * rw;
    const float yoff = 0.25f * bin_h - 0.5f * rh;
    const int py = c / (2 * OUTS);
    const int px = c - py * (2 * OUTS);
    const float yy = (float)py * hbh + yoff;
    const float xx = (float)px * hbw + xoff;
    const float x = xx * ct + yy * st + cx;
    const float y = yy * ct - xx * st + cy;
    int4   o4 = {0, 0, 0, 0};
    float4 w4 = {0.f, 0.f, 0.f, 0.f};
    if (x > -1.0f && x < (float)FW && y > -1.0f && y < (float)FH) {
      float xc = fmaxf(x, 0.f), yc = fmaxf(y, 0.f);
      int x0 = (int)xc, y0 = (int)yc, x1, y1;
      float lx, ly;
      if (x0 >= FW - 1) { x0 = FW - 1; x1 = FW - 1; lx = 0.f; }
      else              { x1 = x0 + 1; lx = xc - (float)x0; }
      if (y0 >= FH - 1) { y0 = FH - 1; y1 = FH - 1; ly = 0.f; }
      else              { y1 = y0 + 1; ly = yc - (float)y0; }
      const float wx0 = 1.f - lx, wy0 = 1.f - ly;
      w4.x = wy0 * wx0; w4.y = wy0 * lx; w4.z = ly * wx0; w4.w = ly * lx;
      o4.x = (y0 * FW + x0) * NCH; o4.y = (y0 * FW + x1) * NCH;
      o4.z = (y1 * FW + x0) * NCH; o4.w = (y1 * FW + x1) * NCH;
    }
    s_off[c] = o4;
    s_w[c]   = w4;
  }
  __syncthreads();

  const half_t* fbb = feat + (size_t)b * (NCH * HW) + c;
  float acc[NBIN];
#pragma unroll
  for (int i = 0; i < NBIN; ++i) acc[i] = 0.f;
#pragma unroll
  for (int py = 0; py < 2 * OUTS; ++py) {
#pragma unroll
    for (int px = 0; px < 2 * OUTS; ++px) {
      const int s = py * (2 * OUTS) + px;
      const int bin = (py >> 1) * OUTS + (px >> 1);
      const int4   o = s_off[s];
      const float4 w = s_w[s];
      acc[bin] += w.x * (float)fbb[o.x] + w.y * (float)fbb[o.y]
                + w.z * (float)fbb[o.z] + w.w * (float)fbb[o.w];
    }
  }
#pragma unroll
  for (int i = 0; i < NBIN; ++i) acc[i] *= 0.25f;

  const float indf = (theta * 8.0f) / 6.2831853071795862f;
  const float ind0 = floorf(indf);
  const float l    = indf - ind0;
  const int   ind  = ((int)ind0) % NORI;
  const int   o    = c & 7;
  const int   lane = c & 63;
  const int srcLane  = (lane & 56) | ((o - ind + 8) & 7);
  const int srcLane2 = (lane & 56) | ((o - ind + 9) & 7);
#pragma unroll
  for (int i = 0; i < NBIN; ++i) {
    const float v  = acc[i];
    const float vs = __shfl(v, srcLane, 64);
    const float vp = __shfl(v, srcLane2, 64);
    acc[i] = (1.f - l) * vs + l * vp;
  }
  const int grp = c >> 6;
#pragma unroll
  for (int g = 0; g < 4; ++g) {
    if (grp == g) {
#pragma unroll
      for (int i = 0; i < NBIN; ++i) s_tr2[(c & 63) * NBIN + i] = acc[i];
    }
    __syncthreads();
    const float4* s4 = (const float4*)s_tr2;
    float4* d4 = (float4*)(out + ((size_t)r * NCH + g * 64) * NBIN);
#pragma unroll
    for (int i = 0; i < 4; ++i) {
      int idx = c + i * 256;
      if (idx < 64 * NBIN / 4) d4[idx] = s4[idx];
    }
    __syncthreads();
  }
}

// ---------------- tier-3 fallback: fp32 NCHW direct ----------------------
__global__ __launch_bounds__(256) void riroi_cf(
    const float* __restrict__ feat, const float* __restrict__ rois,
    float* __restrict__ out) {
  const int r = blockIdx.x;
  const int c = threadIdx.x;
  const float* roi = rois + (size_t)r * 6;
  const int   b     = (int)roi[0];
  const float cx    = roi[1] * 0.25f;
  const float cy    = roi[2] * 0.25f;
  const float rw    = fmaxf(roi[3] * 0.25f, 1.0f);
  const float rh    = fmaxf(roi[4] * 0.25f, 1.0f);
  const float theta = roi[5];
  const float bin_w = rw * (1.0f / OUTS), bin_h = rh * (1.0f / OUTS);
  const float ct = cosf(theta), st = sinf(theta);
  const float hbw = 0.5f * bin_w, hbh = 0.5f * bin_h;
  const float xoff = 0.25f * bin_w - 0.5f * rw;
  const float yoff = 0.25f * bin_h - 0.5f * rh;
  const float* fb = feat + ((size_t)b * NCH + c) * HW;
  float acc[NBIN];
#pragma unroll
  for (int i = 0; i < NBIN; ++i) acc[i] = 0.f;
  for (int py = 0; py < 2 * OUTS; ++py) {
    const float yy = (float)py * hbh + yoff;
    for (int px = 0; px < 2 * OUTS; ++px) {
      const float xx = (float)px * hbw + xoff;
      const float x = xx * ct + yy * st + cx;
      const float y = yy * ct - xx * st + cy;
      if (x > -1.0f && x < (float)FW && y > -1.0f && y < (float)FH) {
        float xc = fmaxf(x, 0.f), yc = fmaxf(y, 0.f);
        int x0 = (int)xc, y0 = (int)yc, x1, y1;
        float lx, ly;
        if (x0 >= FW - 1) { x0 = FW - 1; x1 = FW - 1; lx = 0.f; }
        else              { x1 = x0 + 1; lx = xc - (float)x0; }
        if (y0 >= FH - 1) { y0 = FH - 1; y1 = FH - 1; ly = 0.f; }
        else              { y1 = y0 + 1; ly = yc - (float)y0; }
        const float wx0 = 1.f - lx, wy0 = 1.f - ly;
        acc[(py >> 1) * OUTS + (px >> 1)] +=
            (wy0 * wx0) * fb[y0 * FW + x0] + (wy0 * lx) * fb[y0 * FW + x1]
          + (ly * wx0) * fb[y1 * FW + x0] + (ly * lx) * fb[y1 * FW + x1];
      }
    }
  }
#pragma unroll
  for (int i = 0; i < NBIN; ++i) acc[i] *= 0.25f;
  const float indf = (theta * 8.0f) / 6.2831853071795862f;
  const float ind0 = floorf(indf);
  const float l    = indf - ind0;
  const int   ind  = ((int)ind0) % NORI;
  const int   o    = c & 7;
  const int   lane = c & 63;
  const int srcLane  = (lane & 56) | ((o - ind + 8) & 7);
  const int srcLane2 = (lane & 56) | ((o - ind + 9) & 7);
  float* op = out + ((size_t)r * NCH + c) * NBIN;
#pragma unroll
  for (int i = 0; i < NBIN; ++i) {
    const float v  = acc[i];
    const float vs = __shfl(v, srcLane, 64);
    const float vp = __shfl(v, srcLane2, 64);
    op[i] = (1.f - l) * vs + l * vp;
  }
}

extern "C" void kernel_launch(void* const* d_in, const int* in_sizes, int n_in,
                              void* d_out, int out_size, void* d_ws, size_t ws_size,
                              hipStream_t stream) {
  const float* feat = (const float*)d_in[0];
  const float* rois = (const float*)d_in[1];
  float* out = (float*)d_out;
  const int R = in_sizes[1] / 6;
  const int N = in_sizes[0] / (NCH * HW);

  const size_t geom_bytes = (size_t)R * NSAMP * sizeof(Geom);
  const size_t feat_bytes = (size_t)N * HW * NCH * sizeof(half_t);

  if (ws_size >= geom_bytes + feat_bytes) {
    Geom*   g  = (Geom*)d_ws;
    half_t* ft = (half_t*)((char*)d_ws + geom_bytes);
    dim3 tg(HW / 64, NCH / 64, N);
    transpose_nchw_nhwc_h<<<tg, 256, 0, stream>>>(feat, ft);
    const int total = R * NSAMP;
    geom_kernel<<<(total + 255) / 256, 256, 0, stream>>>(rois, g, total);
    riroi_main<<<R, 512, 0, stream>>>(ft, rois, g, out);
  } else if (ws_size >= feat_bytes) {
    half_t* ft = (half_t*)d_ws;
    dim3 tg(HW / 64, NCH / 64, N);
    transpose_nchw_nhwc_h<<<tg, 256, 0, stream>>>(feat, ft);
    riroi_cl_h<<<R, 256, 0, stream>>>(ft, rois, out);
  } else {
    riroi_cf<<<R, 256, 0, stream>>>(feat, rois, out);
  }
}

// Round 9
// 181.892 us; speedup vs baseline: 2.3978x; 1.0787x over previous
//
#include <hip/hip_runtime.h>

typedef _Float16 half_t;
typedef _Float16 h4 __attribute__((ext_vector_type(4)));
typedef int   v4i __attribute__((ext_vector_type(4)));
typedef float v4f __attribute__((ext_vector_type(4)));

#define OUTS 7
#define NORI 8
#define NCH  256
#define FH   128
#define FW   128
#define HW   (FH * FW)
#define NSAMP (2 * OUTS * 2 * OUTS)  // 196 = 49 bins * 4 subsamples
#define NBIN  (OUTS * OUTS)          // 49
#define WBINS 7                      // bins per wave (8 waves, starts 0,6,...,42)

struct __align__(32) Geom { int o[4]; float w[4]; };

// ---------------- transpose [N,C,H,W] f32 -> [N,H,W,C] f16 ----------------
__global__ __launch_bounds__(256) void transpose_nchw_nhwc_h(
    const float* __restrict__ in, half_t* __restrict__ out) {
  __shared__ float tile[64][65];
  const int b  = blockIdx.z;
  const int p0 = blockIdx.x * 64;
  const int c0 = blockIdx.y * 64;
  const int tx = threadIdx.x & 63;
  const int ty = threadIdx.x >> 6;

  const float* src = in + ((size_t)b * NCH + c0) * HW + p0;
#pragma unroll
  for (int i = 0; i < 16; ++i) {
    int c = ty + i * 4;
    tile[c][tx] = src[(size_t)c * HW + tx];
  }
  __syncthreads();
  half_t* dst = out + ((size_t)b * HW + p0) * NCH + c0;
#pragma unroll
  for (int i = 0; i < 16; ++i) {
    int p = ty + i * 4;
    dst[(size_t)p * NCH + tx] = (half_t)tile[tx][p];
  }
}

// ---------------- geometry precompute: one (roi, sample) per thread ------
// g[r*196 + bin*4 + sub]; byte offsets (batch folded, <<9 = *NCH*2B); weights
// pre-scaled by 0.25 (2x2 sample mean). Nontemporal: keep features hot in L2.
__global__ __launch_bounds__(256) void geom_kernel(
    const float* __restrict__ rois, Geom* __restrict__ g, int total) {
  const int gid = blockIdx.x * 256 + threadIdx.x;
  if (gid >= total) return;
  const int r   = gid / NSAMP;
  const int q   = gid - r * NSAMP;
  const int bin = q >> 2;
  const int sub = q & 3;
  const int by = bin / OUTS, bx = bin - by * OUTS;
  const int py = by * 2 + (sub >> 1);
  const int px = bx * 2 + (sub & 1);

  const float* roi = rois + (size_t)r * 6;
  const int   b     = (int)roi[0];
  const float cx    = roi[1] * 0.25f;
  const float cy    = roi[2] * 0.25f;
  const float rw    = fmaxf(roi[3] * 0.25f, 1.0f);
  const float rh    = fmaxf(roi[4] * 0.25f, 1.0f);
  const float theta = roi[5];
  const float bin_w = rw * (1.0f / OUTS);
  const float bin_h = rh * (1.0f / OUTS);
  const float ct = cosf(theta), st = sinf(theta);
  const float hbw = 0.5f * bin_w, hbh = 0.5f * bin_h;
  const float xoff = 0.25f * bin_w - 0.5f * rw;
  const float yoff = 0.25f * bin_h - 0.5f * rh;

  const float yy = (float)py * hbh + yoff;
  const float xx = (float)px * hbw + xoff;
  const float x = xx * ct + yy * st + cx;
  const float y = yy * ct - xx * st + cy;

  v4i oo = {0, 0, 0, 0};
  v4f ww = {0.f, 0.f, 0.f, 0.f};
  if (x > -1.0f && x < (float)FW && y > -1.0f && y < (float)FH) {
    float xc = fmaxf(x, 0.f);
    float yc = fmaxf(y, 0.f);
    int x0 = (int)xc;
    int y0 = (int)yc;
    int x1, y1;
    float lx, ly;
    if (x0 >= FW - 1) { x0 = FW - 1; x1 = FW - 1; lx = 0.f; }
    else              { x1 = x0 + 1; lx = xc - (float)x0; }
    if (y0 >= FH - 1) { y0 = FH - 1; y1 = FH - 1; ly = 0.f; }
    else              { y1 = y0 + 1; ly = yc - (float)y0; }
    const float wx0 = 1.f - lx, wy0 = 1.f - ly;
    ww.x = 0.25f * wy0 * wx0; ww.y = 0.25f * wy0 * lx;
    ww.z = 0.25f * ly  * wx0; ww.w = 0.25f * ly  * lx;
    const int base = b * HW;
    oo.x = (base + y0 * FW + x0) << 9; oo.y = (base + y0 * FW + x1) << 9;
    oo.z = (base + y1 * FW + x0) << 9; oo.w = (base + y1 * FW + x1) << 9;
  }
  v4i* dst = (v4i*)&g[gid];
  __builtin_nontemporal_store(oo, dst);
  __builtin_nontemporal_store(*(v4i*)&ww, dst + 1);
}

// ---------------- main kernel ---------------------------------------------
// 512 threads = 8 waves; wave w owns bins w*6..w*6+6 (7 bins, boundary bins
// duplicated -- benign). Lane l covers channels 4l..4l+3 via half4 loads.
// Geometry staged in LDS once per block; per-wave 14 batches (2 Geoms each)
// run a 3-stage rotated software pipeline: G=ds_read geom, V=addr+8 global
// loads, F=64 FMAs. Load-issue -> consume distance ~1 full FMA block.
__global__ __launch_bounds__(512) void riroi_main(
    const half_t* __restrict__ feat, const float* __restrict__ rois,
    const Geom* __restrict__ geom, float* __restrict__ out) {
  __shared__ v4i s_geom[NSAMP * 2];               // 6272 B
  __shared__ alignas(16) float s_tr[128 * NBIN];  // 25088 B

  const int r = blockIdx.x;
  const int t = threadIdx.x;
  const int w = t >> 6;
  const int l = t & 63;
  const int b0 = w * 6;
  const int gbase = w * 24;  // b0 * 4 geoms per bin

  // ---- preload this roi's geometry into LDS (coalesced 16B loads) ----
  if (t < NSAMP * 2) s_geom[t] = ((const v4i*)(geom + (size_t)r * NSAMP))[t];
  __syncthreads();

  const float theta = rois[(size_t)r * 6 + 5];  // uniform
  const float indf = theta * (8.0f / 6.2831853071795862f);
  const float ind0 = floorf(indf);
  const float lmix = indf - ind0;
  const int   ind  = ((int)ind0) & 7;
  const int   m    = (8 - ind) & 7;  // T[j] = B[(m+j)&7]

  const char* fb = (const char*)feat;
  const unsigned lane_off = (unsigned)(l << 3);  // 8 B per lane (4 fp16 ch)

  float acc[WBINS][4];
#pragma unroll
  for (int i = 0; i < WBINS; ++i)
#pragma unroll
    for (int j = 0; j < 4; ++j) acc[i][j] = 0.f;

#define DECLSET(S) \
  v4i o0##S, o1##S; v4f w0##S, w1##S; \
  h4 va0##S, va1##S, va2##S, va3##S, vb0##S, vb1##S, vb2##S, vb3##S;
  DECLSET(P) DECLSET(Q) DECLSET(R)
#undef DECLSET

#define GSTAGE(S, bt) { \
  const int gi = gbase + (bt) * 2; \
  o0##S = s_geom[2 * gi];     w0##S = *(const v4f*)&s_geom[2 * gi + 1]; \
  o1##S = s_geom[2 * gi + 2]; w1##S = *(const v4f*)&s_geom[2 * gi + 3]; }

#define VSTAGE(S) { \
  va0##S = *(const h4*)(fb + ((unsigned)o0##S.x + lane_off)); \
  va1##S = *(const h4*)(fb + ((unsigned)o0##S.y + lane_off)); \
  va2##S = *(const h4*)(fb + ((unsigned)o0##S.z + lane_off)); \
  va3##S = *(const h4*)(fb + ((unsigned)o0##S.w + lane_off)); \
  vb0##S = *(const h4*)(fb + ((unsigned)o1##S.x + lane_off)); \
  vb1##S = *(const h4*)(fb + ((unsigned)o1##S.y + lane_off)); \
  vb2##S = *(const h4*)(fb + ((unsigned)o1##S.z + lane_off)); \
  vb3##S = *(const h4*)(fb + ((unsigned)o1##S.w + lane_off)); }

#define FTAP(wv, vk, p) { \
  acc[p][0] += (wv) * (float)(vk)[0]; acc[p][1] += (wv) * (float)(vk)[1]; \
  acc[p][2] += (wv) * (float)(vk)[2]; acc[p][3] += (wv) * (float)(vk)[3]; }

#define FSTAGE(S, p) \
  FTAP(w0##S.x, va0##S, p) FTAP(w0##S.y, va1##S, p) \
  FTAP(w0##S.z, va2##S, p) FTAP(w0##S.w, va3##S, p) \
  FTAP(w1##S.x, vb0##S, p) FTAP(w1##S.y, vb1##S, p) \
  FTAP(w1##S.z, vb2##S, p) FTAP(w1##S.w, vb3##S, p)

#define ITER(bt, S0, S1, S2) { \
  if ((bt) + 2 < 14) GSTAGE(S2, (bt) + 2); \
  if ((bt) + 1 < 14) VSTAGE(S1); \
  FSTAGE(S0, (bt) / 2); }

  // prologue
  GSTAGE(P, 0)
  GSTAGE(Q, 1) VSTAGE(P)
  // 14 batches, 3-set rotation (all indices compile-time)
  ITER(0,  P, Q, R) ITER(1,  Q, R, P) ITER(2,  R, P, Q)
  ITER(3,  P, Q, R) ITER(4,  Q, R, P) ITER(5,  R, P, Q)
  ITER(6,  P, Q, R) ITER(7,  Q, R, P) ITER(8,  R, P, Q)
  ITER(9,  P, Q, R) ITER(10, Q, R, P) ITER(11, R, P, Q)
  ITER(12, P, Q, R) ITER(13, Q, R, P)

#undef ITER
#undef FSTAGE
#undef FTAP
#undef VSTAGE
#undef GSTAGE

  // ---- orientation mix in-register (lane pair holds the 8-group) ----
#define MIX_BODY(M)                                                        \
  {                                                                        \
    _Pragma("unroll")                                                      \
    for (int bb = 0; bb < WBINS; ++bb) {                                   \
      float B[8];                                                          \
      B[0] = acc[bb][0]; B[1] = acc[bb][1];                                \
      B[2] = acc[bb][2]; B[3] = acc[bb][3];                                \
      B[4] = __shfl_xor(acc[bb][0], 1, 64);                                \
      B[5] = __shfl_xor(acc[bb][1], 1, 64);                                \
      B[6] = __shfl_xor(acc[bb][2], 1, 64);                                \
      B[7] = __shfl_xor(acc[bb][3], 1, 64);                                \
      float tt[4];                                                         \
      _Pragma("unroll")                                                    \
      for (int j = 0; j < 4; ++j) {                                        \
        const float a0 = B[((M) + j) & 7];                                 \
        const float a1 = B[((M) + j + 1) & 7];                             \
        tt[j] = a0 + lmix * (a1 - a0);                                     \
      }                                                                    \
      acc[bb][0] = tt[0]; acc[bb][1] = tt[1];                              \
      acc[bb][2] = tt[2]; acc[bb][3] = tt[3];                              \
    }                                                                      \
  }
  switch (m) {
    case 0: MIX_BODY(0) break;
    case 1: MIX_BODY(1) break;
    case 2: MIX_BODY(2) break;
    case 3: MIX_BODY(3) break;
    case 4: MIX_BODY(4) break;
    case 5: MIX_BODY(5) break;
    case 6: MIX_BODY(6) break;
    case 7: MIX_BODY(7) break;
  }
#undef MIX_BODY

  // ---- 2 channel-rounds: stage [128ch][49bin] in LDS, nt-copy coalesced ----
#pragma unroll
  for (int rnd = 0; rnd < 2; ++rnd) {
    if ((l >> 5) == rnd) {
      const int cl = (l & 31) * 4;  // local channel base 0..124
#pragma unroll
      for (int bb = 0; bb < WBINS; ++bb) {
        const int bin = b0 + bb;
#pragma unroll
        for (int j = 0; j < 4; ++j)
          s_tr[(cl + j) * NBIN + bin] = acc[bb][j];
      }
    }
    __syncthreads();
    const v4f* s4 = (const v4f*)s_tr;
    v4f* d4 = (v4f*)(out + (size_t)r * (NCH * NBIN) + rnd * (128 * NBIN));
    for (int i = t; i < 128 * NBIN / 4; i += 512)
      __builtin_nontemporal_store(s4[i], d4 + i);
    __syncthreads();
  }
}

// ---------------- tier-2 fallback: LDS-geometry channels-last fp16 --------
__global__ __launch_bounds__(256) void riroi_cl_h(
    const half_t* __restrict__ feat, const float* __restrict__ rois,
    float* __restrict__ out) {
  __shared__ int4   s_off[NSAMP];
  __shared__ float4 s_w[NSAMP];
  __shared__ alignas(16) float s_tr2[64 * NBIN];

  const int r = blockIdx.x;
  const int c = threadIdx.x;
  const float* roi = rois + (size_t)r * 6;
  const int   b     = (int)roi[0];
  const float theta = roi[5];

  if (c < NSAMP) {
    const float cx = roi[1] * 0.25f;
    const float cy = roi[2] * 0.25f;
    const float rw = fmaxf(roi[3] * 0.25f, 1.0f);
    const float rh = fmaxf(roi[4] * 0.25f, 1.0f);
    const float bin_w = rw * (1.0f / OUTS);
    const float bin_h = rh * (1.0f / OUTS);
    const float ct = cosf(theta), st = sinf(theta);
    const float hbw = 0.5f * bin_w, hbh = 0.5f * bin_h;
    const float xoff = 0.25f * bin_w - 0.5f * rw;
    const float yoff = 0.25f * bin_h - 0.5f * rh;
    const int py = c / (2 * OUTS);
    const int px = c - py * (2 * OUTS);
    const float yy = (float)py * hbh + yoff;
    const float xx = (float)px * hbw + xoff;
    const float x = xx * ct + yy * st + cx;
    const float y = yy * ct - xx * st + cy;
    int4   o4 = {0, 0, 0, 0};
    float4 w4 = {0.f, 0.f, 0.f, 0.f};
    if (x > -1.0f && x < (float)FW && y > -1.0f && y < (float)FH) {
      float xc = fmaxf(x, 0.f), yc = fmaxf(y, 0.f);
      int x0 = (int)xc, y0 = (int)yc, x1, y1;
      float lx, ly;
      if (x0 >= FW - 1) { x0 = FW - 1; x1 = FW - 1; lx = 0.f; }
      else              { x1 = x0 + 1; lx = xc - (float)x0; }
      if (y0 >= FH - 1) { y0 = FH - 1; y1 = FH - 1; ly = 0.f; }
      else              { y1 = y0 + 1; ly = yc - (float)y0; }
      const float wx0 = 1.f - lx, wy0 = 1.f - ly;
      w4.x = wy0 * wx0; w4.y = wy0 * lx; w4.z = ly * wx0; w4.w = ly * lx;
      o4.x = (y0 * FW + x0) * NCH; o4.y = (y0 * FW + x1) * NCH;
      o4.z = (y1 * FW + x0) * NCH; o4.w = (y1 * FW + x1) * NCH;
    }
    s_off[c] = o4;
    s_w[c]   = w4;
  }
  __syncthreads();

  const half_t* fbb = feat + (size_t)b * (NCH * HW) + c;
  float acc[NBIN];
#pragma unroll
  for (int i = 0; i < NBIN; ++i) acc[i] = 0.f;
#pragma unroll
  for (int py = 0; py < 2 * OUTS; ++py) {
#pragma unroll
    for (int px = 0; px < 2 * OUTS; ++px) {
      const int s = py * (2 * OUTS) + px;
      const int bin = (py >> 1) * OUTS + (px >> 1);
      const int4   o = s_off[s];
      const float4 w = s_w[s];
      acc[bin] += w.x * (float)fbb[o.x] + w.y * (float)fbb[o.y]
                + w.z * (float)fbb[o.z] + w.w * (float)fbb[o.w];
    }
  }
#pragma unroll
  for (int i = 0; i < NBIN; ++i) acc[i] *= 0.25f;

  const float indf = (theta * 8.0f) / 6.2831853071795862f;
  const float ind0 = floorf(indf);
  const float l    = indf - ind0;
  const int   ind  = ((int)ind0) % NORI;
  const int   o    = c & 7;
  const int   lane = c & 63;
  const int srcLane  = (lane & 56) | ((o - ind + 8) & 7);
  const int srcLane2 = (lane & 56) | ((o - ind + 9) & 7);
#pragma unroll
  for (int i = 0; i < NBIN; ++i) {
    const float v  = acc[i];
    const float vs = __shfl(v, srcLane, 64);
    const float vp = __shfl(v, srcLane2, 64);
    acc[i] = (1.f - l) * vs + l * vp;
  }
  const int grp = c >> 6;
#pragma unroll
  for (int g = 0; g < 4; ++g) {
    if (grp == g) {
#pragma unroll
      for (int i = 0; i < NBIN; ++i) s_tr2[(c & 63) * NBIN + i] = acc[i];
    }
    __syncthreads();
    const float4* s4 = (const float4*)s_tr2;
    float4* d4 = (float4*)(out + ((size_t)r * NCH + g * 64) * NBIN);
#pragma unroll
    for (int i = 0; i < 4; ++i) {
      int idx = c + i * 256;
      if (idx < 64 * NBIN / 4) d4[idx] = s4[idx];
    }
    __syncthreads();
  }
}

// ---------------- tier-3 fallback: fp32 NCHW direct ----------------------
__global__ __launch_bounds__(256) void riroi_cf(
    const float* __restrict__ feat, const float* __restrict__ rois,
    float* __restrict__ out) {
  const int r = blockIdx.x;
  const int c = threadIdx.x;
  const float* roi = rois + (size_t)r * 6;
  const int   b     = (int)roi[0];
  const float cx    = roi[1] * 0.25f;
  const float cy    = roi[2] * 0.25f;
  const float rw    = fmaxf(roi[3] * 0.25f, 1.0f);
  const float rh    = fmaxf(roi[4] * 0.25f, 1.0f);
  const float theta = roi[5];
  const float bin_w = rw * (1.0f / OUTS), bin_h = rh * (1.0f / OUTS);
  const float ct = cosf(theta), st = sinf(theta);
  const float hbw = 0.5f * bin_w, hbh = 0.5f * bin_h;
  const float xoff = 0.25f * bin_w - 0.5f * rw;
  const float yoff = 0.25f * bin_h - 0.5f * rh;
  const float* fb = feat + ((size_t)b * NCH + c) * HW;
  float acc[NBIN];
#pragma unroll
  for (int i = 0; i < NBIN; ++i) acc[i] = 0.f;
  for (int py = 0; py < 2 * OUTS; ++py) {
    const float yy = (float)py * hbh + yoff;
    for (int px = 0; px < 2 * OUTS; ++px) {
      const float xx = (float)px * hbw + xoff;
      const float x = xx * ct + yy * st + cx;
      const float y = yy * ct - xx * st + cy;
      if (x > -1.0f && x < (float)FW && y > -1.0f && y < (float)FH) {
        float xc = fmaxf(x, 0.f), yc = fmaxf(y, 0.f);
        int x0 = (int)xc, y0 = (int)yc, x1, y1;
        float lx, ly;
        if (x0 >= FW - 1) { x0 = FW - 1; x1 = FW - 1; lx = 0.f; }
        else              { x1 = x0 + 1; lx = xc - (float)x0; }
        if (y0 >= FH - 1) { y0 = FH - 1; y1 = FH - 1; ly = 0.f; }
        else              { y1 = y0 + 1; ly = yc - (float)y0; }
        const float wx0 = 1.f - lx, wy0 = 1.f - ly;
        acc[(py >> 1) * OUTS + (px >> 1)] +=
            (wy0 * wx0) * fb[y0 * FW + x0] + (wy0 * lx) * fb[y0 * FW + x1]
          + (ly * wx0) * fb[y1 * FW + x0] + (ly * lx) * fb[y1 * FW + x1];
      }
    }
  }
#pragma unroll
  for (int i = 0; i < NBIN; ++i) acc[i] *= 0.25f;
  const float indf = (theta * 8.0f) / 6.2831853071795862f;
  const float ind0 = floorf(indf);
  const float l    = indf - ind0;
  const int   ind  = ((int)ind0) % NORI;
  const int   o    = c & 7;
  const int   lane = c & 63;
  const int srcLane  = (lane & 56) | ((o - ind + 8) & 7);
  const int srcLane2 = (lane & 56) | ((o - ind + 9) & 7);
  float* op = out + ((size_t)r * NCH + c) * NBIN;
#pragma unroll
  for (int i = 0; i < NBIN; ++i) {
    const float v  = acc[i];
    const float vs = __shfl(v, srcLane, 64);
    const float vp = __shfl(v, srcLane2, 64);
    op[i] = (1.f - l) * vs + l * vp;
  }
}

extern "C" void kernel_launch(void* const* d_in, const int* in_sizes, int n_in,
                              void* d_out, int out_size, void* d_ws, size_t ws_size,
                              hipStream_t stream) {
  const float* feat = (const float*)d_in[0];
  const float* rois = (const float*)d_in[1];
  float* out = (float*)d_out;
  const int R = in_sizes[1] / 6;
  const int N = in_sizes[0] / (NCH * HW);

  const size_t geom_bytes = (size_t)R * NSAMP * sizeof(Geom);
  const size_t feat_bytes = (size_t)N * HW * NCH * sizeof(half_t);

  if (ws_size >= geom_bytes + feat_bytes) {
    Geom*   g  = (Geom*)d_ws;
    half_t* ft = (half_t*)((char*)d_ws + geom_bytes);
    dim3 tg(HW / 64, NCH / 64, N);
    transpose_nchw_nhwc_h<<<tg, 256, 0, stream>>>(feat, ft);
    const int total = R * NSAMP;
    geom_kernel<<<(total + 255) / 256, 256, 0, stream>>>(rois, g, total);
    riroi_main<<<R, 512, 0, stream>>>(ft, rois, g, out);
  } else if (ws_size >= feat_bytes) {
    half_t* ft = (half_t*)d_ws;
    dim3 tg(HW / 64, NCH / 64, N);
    transpose_nchw_nhwc_h<<<tg, 256, 0, stream>>>(feat, ft);
    riroi_cl_h<<<R, 256, 0, stream>>>(ft, rois, out);
  } else {
    riroi_cf<<<R, 256, 0, stream>>>(feat, rois, out);
  }
}